// Round 8
// baseline (3293.019 us; speedup 1.0000x reference)
//
#include <hip/hip_runtime.h>
#include <cstdint>
#include <cstddef>

typedef __attribute__((ext_vector_type(4))) float f4;
typedef __attribute__((ext_vector_type(4))) int i32x4;
typedef __attribute__((ext_vector_type(4))) char c4;

#define HID 4096
#define INTER 14336
#define QMAX 127.0f

// ---------- helpers ----------

typedef __attribute__((address_space(1))) const void* as1_cvp;
typedef __attribute__((address_space(3))) void* as3_vp;

// async global->LDS, 16 B per lane; LDS dest = wave-uniform base + lane*16
__device__ __forceinline__ void async_ld16(void* lds, const void* g) {
  __builtin_amdgcn_global_load_lds((as1_cvp)g, (as3_vp)lds, 16, 0, 0);
}

// ---------- 64x64 kron transform + 8-bit fake quant (per row) ----------
// dst[row] = quantint( L^T * ((src[row] {*,/} diag).reshape(64,64)) * R ) as int8
__global__ __launch_bounds__(256) void trans64_kernel(
    const float* __restrict__ src, const float* __restrict__ Lm,
    const float* __restrict__ Rm, const float* __restrict__ dia,
    signed char* __restrict__ dst, float* __restrict__ dscale, int divide)
{
  __shared__ float sX[64 * 68];   // padded stride 68 (bank-conflict break)
  __shared__ float sT[64 * 68];
  __shared__ float sL[64 * 64];
  __shared__ float sR[64 * 64];
  __shared__ float sred[8];

  const int tid = threadIdx.x;
  const int w = tid >> 6, lane = tid & 63;
  const size_t row = blockIdx.x;
  const float* srow = src + row * (size_t)HID;

  for (int i = tid * 4; i < 64 * 64; i += 1024) {
    *(f4*)&sL[i] = *(const f4*)&Lm[i];
    *(f4*)&sR[i] = *(const f4*)&Rm[i];
  }
  for (int i = tid * 4; i < HID; i += 1024) {
    f4 v = *(const f4*)&srow[i];
    f4 d = *(const f4*)&dia[i];
    v = divide ? (v / d) : (v * d);
    const int l = i >> 6, r = i & 63;
    *(f4*)&sX[l * 68 + r] = v;
  }
  __syncthreads();

  const int a = tid >> 4, b = tid & 15;  // thread computes 4x4 outputs
  f4 acc[4];
  acc[0] = 0.f; acc[1] = 0.f; acc[2] = 0.f; acc[3] = 0.f;
  // phase 1: T1[i][r] = sum_l L[l][i] * X[l][r]
  #pragma unroll 4
  for (int l = 0; l < 64; ++l) {
    const f4 lv = *(const f4*)&sL[l * 64 + a * 4];
    const f4 xv = *(const f4*)&sX[l * 68 + b * 4];
    acc[0] += lv[0] * xv;
    acc[1] += lv[1] * xv;
    acc[2] += lv[2] * xv;
    acc[3] += lv[3] * xv;
  }
  #pragma unroll
  for (int u = 0; u < 4; ++u)
    *(f4*)&sT[(a * 4 + u) * 68 + b * 4] = acc[u];
  __syncthreads();

  // phase 2: Y[i][j] = sum_r T1[i][r] * R[r][j]
  f4 y[4];
  y[0] = 0.f; y[1] = 0.f; y[2] = 0.f; y[3] = 0.f;
  #pragma unroll 4
  for (int r = 0; r < 64; ++r) {
    const f4 rv = *(const f4*)&sR[r * 64 + b * 4];
    y[0] += sT[(a * 4 + 0) * 68 + r] * rv;
    y[1] += sT[(a * 4 + 1) * 68 + r] * rv;
    y[2] += sT[(a * 4 + 2) * 68 + r] * rv;
    y[3] += sT[(a * 4 + 3) * 68 + r] * rv;
  }

  // row absmax -> scale
  float m = 0.f;
  #pragma unroll
  for (int u = 0; u < 4; ++u)
    #pragma unroll
    for (int v = 0; v < 4; ++v) m = fmaxf(m, fabsf(y[u][v]));
  #pragma unroll
  for (int off = 32; off > 0; off >>= 1) m = fmaxf(m, __shfl_down(m, off));
  if (lane == 0) sred[w] = m;
  __syncthreads();
  if (tid == 0) {
    const float mm = fmaxf(fmaxf(sred[0], sred[1]), fmaxf(sred[2], sred[3]));
    const float s = fmaxf(mm / QMAX, 1e-8f);
    dscale[row] = s;
    sred[4] = s;
  }
  __syncthreads();
  const float s = sred[4];

  signed char* drow = dst + row * (size_t)HID;
  #pragma unroll
  for (int u = 0; u < 4; ++u) {
    c4 o;
    #pragma unroll
    for (int v = 0; v < 4; ++v) {
      float q = y[u][v] / s;
      q = fminf(fmaxf(q, -QMAX), QMAX);
      q = rintf(q);                 // round-half-even, matches jnp.round
      o[v] = (char)(int)q;
    }
    *(c4*)&drow[(a * 4 + u) * 64 + b * 4] = o;
  }
}

// ---------- 112x128 kron transform + 8-bit fake quant (per row) ----------
__global__ __launch_bounds__(512) void trans112_kernel(
    const float* __restrict__ src, const float* __restrict__ Lm,  // [112][112]
    const float* __restrict__ Rm,                                  // [128][128]
    const float* __restrict__ dia,                                 // [14336]
    signed char* __restrict__ dst, float* __restrict__ dscale, int divide)
{
  __shared__ float sH[112 * 132];  // padded stride 132
  __shared__ float sT[112 * 132];
  __shared__ float sC[16 * 132];   // L/R row-chunk staging
  __shared__ float sred[16];

  const int tid = threadIdx.x;
  const int w = tid >> 6, lane = tid & 63;
  const size_t row = blockIdx.x;
  const float* srow = src + row * (size_t)INTER;

  for (int i = tid * 4; i < INTER; i += 2048) {
    f4 v = *(const f4*)&srow[i];
    f4 d = *(const f4*)&dia[i];
    v = divide ? (v / d) : (v * d);
    const int l = i >> 7, r = i & 127;
    *(f4*)&sH[l * 132 + r] = v;
  }
  __syncthreads();

  const int a = tid >> 5;  // 0..15 -> i block of 7
  const int b = tid & 31;  // 0..31 -> 4-wide col block
  f4 acc[7];
  #pragma unroll
  for (int u = 0; u < 7; ++u) acc[u] = 0.f;

  // phase 1: T1[i][r] = sum_l L[l][i] * H[l][r]
  for (int l0 = 0; l0 < 112; l0 += 16) {
    __syncthreads();
    for (int i = tid; i < 16 * 112; i += 512)
      sC[(i / 112) * 132 + (i % 112)] = Lm[(l0 + i / 112) * 112 + (i % 112)];
    __syncthreads();
    #pragma unroll
    for (int lc = 0; lc < 16; ++lc) {
      const f4 hv = *(const f4*)&sH[(l0 + lc) * 132 + b * 4];
      #pragma unroll
      for (int u = 0; u < 7; ++u)
        acc[u] += sC[lc * 132 + a * 7 + u] * hv;
    }
  }
  #pragma unroll
  for (int u = 0; u < 7; ++u)
    *(f4*)&sT[(a * 7 + u) * 132 + b * 4] = acc[u];

  // phase 2: Y[i][j] = sum_r T1[i][r] * R[r][j]
  f4 y[7];
  #pragma unroll
  for (int u = 0; u < 7; ++u) y[u] = 0.f;
  for (int r0 = 0; r0 < 128; r0 += 16) {
    __syncthreads();  // also publishes sT on first pass, protects sC reuse
    for (int i = tid; i < 16 * 128; i += 512)
      sC[(i >> 7) * 132 + (i & 127)] = Rm[(r0 + (i >> 7)) * 128 + (i & 127)];
    __syncthreads();
    #pragma unroll
    for (int rc = 0; rc < 16; ++rc) {
      const f4 rv = *(const f4*)&sC[rc * 132 + b * 4];
      #pragma unroll
      for (int u = 0; u < 7; ++u)
        y[u] += sT[(a * 7 + u) * 132 + r0 + rc] * rv;
    }
  }

  float m = 0.f;
  #pragma unroll
  for (int u = 0; u < 7; ++u)
    #pragma unroll
    for (int v = 0; v < 4; ++v) m = fmaxf(m, fabsf(y[u][v]));
  #pragma unroll
  for (int off = 32; off > 0; off >>= 1) m = fmaxf(m, __shfl_down(m, off));
  if (lane == 0) sred[w] = m;
  __syncthreads();
  if (tid == 0) {
    float mm = sred[0];
    #pragma unroll
    for (int i = 1; i < 8; ++i) mm = fmaxf(mm, sred[i]);
    const float s = fmaxf(mm / QMAX, 1e-8f);
    dscale[row] = s;
    sred[8] = s;
  }
  __syncthreads();
  const float s = sred[8];

  signed char* drow = dst + row * (size_t)INTER;
  #pragma unroll
  for (int u = 0; u < 7; ++u) {
    c4 o;
    #pragma unroll
    for (int v = 0; v < 4; ++v) {
      float q = y[u][v] / s;
      q = fminf(fmaxf(q, -QMAX), QMAX);
      q = rintf(q);
      o[v] = (char)(int)q;
    }
    *(c4*)&drow[(a * 7 + u) * 128 + b * 4] = o;
  }
}

// ---------- fused up+gate GEMM (int8 MFMA, i32 exact accum) + SwiGLU ----------
// C-tile: 128 rows (tokens) x 64 cols (o) of BOTH matrices; wave = 64x32 of both.
// BK=128 int8: same 32 KB LDS / same staging addressing as the bf16 BK=64 version,
// but 2x FLOP per staged byte and half the barriers per K.
// NOTE: grid-x = 224 ≡ 0 mod 8 -> blocks sharing a B-panel (same bx) land on the
// same XCD under round-robin dispatch; do NOT swizzle (it would break this).
__global__ __launch_bounds__(256) void gemm_upgate_kernel(
    const signed char* __restrict__ xq, const signed char* __restrict__ wu,
    const signed char* __restrict__ wg, const float* __restrict__ sx,
    const float* __restrict__ swu, const float* __restrict__ swg,
    float* __restrict__ h)
{
  __shared__ __attribute__((aligned(16))) signed char As[128 * 128];  // 16 KB
  __shared__ __attribute__((aligned(16))) signed char Bu[64 * 128];   // 8 KB
  __shared__ __attribute__((aligned(16))) signed char Bg[64 * 128];   // 8 KB

  const int tid = threadIdx.x;
  const int w = tid >> 6, lane = tid & 63;
  const int quad = lane >> 4, l16 = lane & 15;
  const int wm = w & 1, wn = w >> 1;
  const int n0 = blockIdx.x * 64;
  const int m0 = blockIdx.y * 128;
  const int srow = lane >> 3;           // row within 8-row staging chunk
  const int scolb = (lane & 7) * 16;    // byte col within 128-B row

  const i32x4 z4 = {0, 0, 0, 0};
  i32x4 accu[4][2], accg[4][2];
  #pragma unroll
  for (int mi = 0; mi < 4; ++mi)
    #pragma unroll
    for (int ni = 0; ni < 2; ++ni) { accu[mi][ni] = z4; accg[mi][ni] = z4; }

  for (int k0 = 0; k0 < HID; k0 += 128) {
    __syncthreads();
    #pragma unroll
    for (int i = 0; i < 4; ++i) {  // A: 16 chunks of 1 KB (128 rows x 128 B)
      const int c = i * 4 + w;
      const int r = c * 8 + srow;
      async_ld16((char*)As + c * 1024,
                 (const char*)xq + (size_t)(m0 + r) * HID + k0 + scolb);
    }
    #pragma unroll
    for (int i = 0; i < 2; ++i) {  // Bu/Bg: 8 chunks each (64 rows x 128 B)
      const int c = i * 4 + w;
      const int r = c * 8 + srow;
      async_ld16((char*)Bu + c * 1024,
                 (const char*)wu + (size_t)(n0 + r) * HID + k0 + scolb);
      async_ld16((char*)Bg + c * 1024,
                 (const char*)wg + (size_t)(n0 + r) * HID + k0 + scolb);
    }
    __syncthreads();  // drains vmcnt -> staged data visible

    #pragma unroll
    for (int kk = 0; kk < 128; kk += 64) {
      i32x4 af[4], buf_[2], bgf[2];
      #pragma unroll
      for (int mi = 0; mi < 4; ++mi)
        af[mi] = *(const i32x4*)&As[(wm * 64 + mi * 16 + l16) * 128 + kk + quad * 16];
      #pragma unroll
      for (int ni = 0; ni < 2; ++ni) {
        buf_[ni] = *(const i32x4*)&Bu[(wn * 32 + ni * 16 + l16) * 128 + kk + quad * 16];
        bgf[ni] = *(const i32x4*)&Bg[(wn * 32 + ni * 16 + l16) * 128 + kk + quad * 16];
      }
      #pragma unroll
      for (int mi = 0; mi < 4; ++mi)
        #pragma unroll
        for (int ni = 0; ni < 2; ++ni) {
          accu[mi][ni] = __builtin_amdgcn_mfma_i32_16x16x64_i8(af[mi], buf_[ni], accu[mi][ni], 0, 0, 0);
          accg[mi][ni] = __builtin_amdgcn_mfma_i32_16x16x64_i8(af[mi], bgf[ni], accg[mi][ni], 0, 0, 0);
        }
    }
  }

  // epilogue: dequant scales + SwiGLU, store h fp32
  #pragma unroll
  for (int mi = 0; mi < 4; ++mi) {
    const int tb = m0 + wm * 64 + mi * 16 + quad * 4;
    float sxv[4];
    #pragma unroll
    for (int r = 0; r < 4; ++r) sxv[r] = sx[tb + r];
    #pragma unroll
    for (int ni = 0; ni < 2; ++ni) {
      const int o = n0 + wn * 32 + ni * 16 + l16;
      const float su = swu[o], sg = swg[o];
      #pragma unroll
      for (int r = 0; r < 4; ++r) {
        const float uv = (float)accu[mi][ni][r] * sxv[r] * su;
        const float gv = (float)accg[mi][ni][r] * sxv[r] * sg;
        const float hv = gv / (1.f + __expf(-gv)) * uv;  // silu(g)*u
        h[(size_t)(tb + r) * INTER + o] = hv;
      }
    }
  }
}

// ---------- down GEMM (int8 MFMA), 128x128 tile ----------
__global__ __launch_bounds__(256) void gemm_down_kernel(
    const signed char* __restrict__ hq, const signed char* __restrict__ wd,
    const float* __restrict__ sh, const float* __restrict__ swd,
    float* __restrict__ out)
{
  __shared__ __attribute__((aligned(16))) signed char As[128 * 128];  // 16 KB
  __shared__ __attribute__((aligned(16))) signed char Bs[128 * 128];  // 16 KB

  const int tid = threadIdx.x;
  const int w = tid >> 6, lane = tid & 63;
  const int quad = lane >> 4, l16 = lane & 15;
  const int wm = w & 1, wn = w >> 1;
  const int n0 = blockIdx.x * 128;
  const int m0 = blockIdx.y * 128;
  const int srow = lane >> 3;
  const int scolb = (lane & 7) * 16;

  const i32x4 z4 = {0, 0, 0, 0};
  i32x4 acc[4][4];
  #pragma unroll
  for (int mi = 0; mi < 4; ++mi)
    #pragma unroll
    for (int ni = 0; ni < 4; ++ni) acc[mi][ni] = z4;

  for (int k0 = 0; k0 < INTER; k0 += 128) {
    __syncthreads();
    #pragma unroll
    for (int i = 0; i < 4; ++i) {
      const int c = i * 4 + w;
      const int r = c * 8 + srow;
      async_ld16((char*)As + c * 1024,
                 (const char*)hq + (size_t)(m0 + r) * INTER + k0 + scolb);
      async_ld16((char*)Bs + c * 1024,
                 (const char*)wd + (size_t)(n0 + r) * INTER + k0 + scolb);
    }
    __syncthreads();

    #pragma unroll
    for (int kk = 0; kk < 128; kk += 64) {
      i32x4 af[4], bf_[4];
      #pragma unroll
      for (int mi = 0; mi < 4; ++mi)
        af[mi] = *(const i32x4*)&As[(wm * 64 + mi * 16 + l16) * 128 + kk + quad * 16];
      #pragma unroll
      for (int ni = 0; ni < 4; ++ni)
        bf_[ni] = *(const i32x4*)&Bs[(wn * 64 + ni * 16 + l16) * 128 + kk + quad * 16];
      #pragma unroll
      for (int mi = 0; mi < 4; ++mi)
        #pragma unroll
        for (int ni = 0; ni < 4; ++ni)
          acc[mi][ni] = __builtin_amdgcn_mfma_i32_16x16x64_i8(af[mi], bf_[ni], acc[mi][ni], 0, 0, 0);
    }
  }

  #pragma unroll
  for (int mi = 0; mi < 4; ++mi) {
    const int tb = m0 + wm * 64 + mi * 16 + quad * 4;
    float shv[4];
    #pragma unroll
    for (int r = 0; r < 4; ++r) shv[r] = sh[tb + r];
    #pragma unroll
    for (int ni = 0; ni < 4; ++ni) {
      const int o = n0 + wn * 64 + ni * 16 + l16;
      const float sw = swd[o];
      #pragma unroll
      for (int r = 0; r < 4; ++r)
        out[(size_t)(tb + r) * HID + o] = (float)acc[mi][ni][r] * shv[r] * sw;
    }
  }
}

// ---------- launch ----------
extern "C" void kernel_launch(void* const* d_in, const int* in_sizes, int n_in,
                              void* d_out, int out_size, void* d_ws, size_t ws_size,
                              hipStream_t stream) {
  const float* x      = (const float*)d_in[0];
  const float* w_up   = (const float*)d_in[1];
  const float* w_gate = (const float*)d_in[2];
  const float* w_down = (const float*)d_in[3];
  const float* ugL    = (const float*)d_in[4];
  const float* ugR    = (const float*)d_in[5];
  const float* ugd    = (const float*)d_in[6];
  const float* dnL    = (const float*)d_in[7];
  const float* dnR    = (const float*)d_in[8];
  const float* dnd    = (const float*)d_in[9];

  char* ws = (char*)d_ws;
  size_t off = 0;
  auto alloc = [&](size_t bytes) {
    char* p = ws + off;
    off = (off + bytes + 255) & ~(size_t)255;
    return p;
  };
  signed char* wqu = (signed char*)alloc((size_t)INTER * HID);        // 58.7 MB
  signed char* wqg = (signed char*)alloc((size_t)INTER * HID);        // 58.7 MB
  signed char* wqd = (signed char*)alloc((size_t)HID * INTER);        // 58.7 MB
  signed char* xq  = (signed char*)alloc((size_t)4096 * HID);         // 16.8 MB
  signed char* hq  = (signed char*)alloc((size_t)4096 * INTER);       // 58.7 MB
  float* hbuf = (float*)alloc((size_t)4096 * INTER * 4);              // 235 MB
  float* sxs  = (float*)alloc((size_t)4096 * 4);
  float* swu  = (float*)alloc((size_t)INTER * 4);
  float* swg  = (float*)alloc((size_t)INTER * 4);
  float* swd  = (float*)alloc((size_t)HID * 4);
  float* shs  = (float*)alloc((size_t)4096 * 4);

  // weight prep (orthogonal L,R: inv == transpose, so weight transform == L^T (W/d) R)
  hipLaunchKernelGGL(trans64_kernel, dim3(INTER), dim3(256), 0, stream,
                     w_up, ugL, ugR, ugd, wqu, swu, 1);
  hipLaunchKernelGGL(trans64_kernel, dim3(INTER), dim3(256), 0, stream,
                     w_gate, ugL, ugR, ugd, wqg, swg, 1);
  hipLaunchKernelGGL(trans112_kernel, dim3(HID), dim3(512), 0, stream,
                     w_down, dnL, dnR, dnd, wqd, swd, 1);
  // activation transform + quant
  hipLaunchKernelGGL(trans64_kernel, dim3(4096), dim3(256), 0, stream,
                     x, ugL, ugR, ugd, xq, sxs, 0);
  // fused up/gate GEMM + SwiGLU
  hipLaunchKernelGGL(gemm_upgate_kernel, dim3(INTER / 64, 4096 / 128), dim3(256), 0, stream,
                     xq, wqu, wqg, sxs, swu, swg, hbuf);
  // h transform + quant
  hipLaunchKernelGGL(trans112_kernel, dim3(4096), dim3(512), 0, stream,
                     hbuf, dnL, dnR, dnd, hq, shs, 0);
  // down GEMM -> out
  hipLaunchKernelGGL(gemm_down_kernel, dim3(HID / 128, 4096 / 128), dim3(256), 0, stream,
                     hq, wqd, shs, swd, (float*)d_out);
}

// Round 9
// 3101.197 us; speedup vs baseline: 1.0619x; 1.0619x over previous
//
#include <hip/hip_runtime.h>
#include <cstdint>
#include <cstddef>

typedef __attribute__((ext_vector_type(4))) float f4;
typedef __attribute__((ext_vector_type(4))) int i32x4;
typedef __attribute__((ext_vector_type(4))) char c4;

#define HID 4096
#define INTER 14336
#define QMAX 127.0f

// ---------- helpers ----------

typedef __attribute__((address_space(1))) const void* as1_cvp;
typedef __attribute__((address_space(3))) void* as3_vp;

// async global->LDS, 16 B per lane; LDS dest = wave-uniform base + lane*16
__device__ __forceinline__ void async_ld16(void* lds, const void* g) {
  __builtin_amdgcn_global_load_lds((as1_cvp)g, (as3_vp)lds, 16, 0, 0);
}

// ---------- 64x64 kron transform + 8-bit fake quant (per row) ----------
// dst[row] = quantint( L^T * ((src[row] {*,/} diag).reshape(64,64)) * R ) as int8
__global__ __launch_bounds__(256) void trans64_kernel(
    const float* __restrict__ src, const float* __restrict__ Lm,
    const float* __restrict__ Rm, const float* __restrict__ dia,
    signed char* __restrict__ dst, float* __restrict__ dscale, int divide)
{
  __shared__ float sX[64 * 68];   // padded stride 68 (bank-conflict break)
  __shared__ float sT[64 * 68];
  __shared__ float sL[64 * 64];
  __shared__ float sR[64 * 64];
  __shared__ float sred[8];

  const int tid = threadIdx.x;
  const int w = tid >> 6, lane = tid & 63;
  const size_t row = blockIdx.x;
  const float* srow = src + row * (size_t)HID;

  for (int i = tid * 4; i < 64 * 64; i += 1024) {
    *(f4*)&sL[i] = *(const f4*)&Lm[i];
    *(f4*)&sR[i] = *(const f4*)&Rm[i];
  }
  for (int i = tid * 4; i < HID; i += 1024) {
    f4 v = *(const f4*)&srow[i];
    f4 d = *(const f4*)&dia[i];
    v = divide ? (v / d) : (v * d);
    const int l = i >> 6, r = i & 63;
    *(f4*)&sX[l * 68 + r] = v;
  }
  __syncthreads();

  const int a = tid >> 4, b = tid & 15;  // thread computes 4x4 outputs
  f4 acc[4];
  acc[0] = 0.f; acc[1] = 0.f; acc[2] = 0.f; acc[3] = 0.f;
  // phase 1: T1[i][r] = sum_l L[l][i] * X[l][r]
  #pragma unroll 4
  for (int l = 0; l < 64; ++l) {
    const f4 lv = *(const f4*)&sL[l * 64 + a * 4];
    const f4 xv = *(const f4*)&sX[l * 68 + b * 4];
    acc[0] += lv[0] * xv;
    acc[1] += lv[1] * xv;
    acc[2] += lv[2] * xv;
    acc[3] += lv[3] * xv;
  }
  #pragma unroll
  for (int u = 0; u < 4; ++u)
    *(f4*)&sT[(a * 4 + u) * 68 + b * 4] = acc[u];
  __syncthreads();

  // phase 2: Y[i][j] = sum_r T1[i][r] * R[r][j]
  f4 y[4];
  y[0] = 0.f; y[1] = 0.f; y[2] = 0.f; y[3] = 0.f;
  #pragma unroll 4
  for (int r = 0; r < 64; ++r) {
    const f4 rv = *(const f4*)&sR[r * 64 + b * 4];
    y[0] += sT[(a * 4 + 0) * 68 + r] * rv;
    y[1] += sT[(a * 4 + 1) * 68 + r] * rv;
    y[2] += sT[(a * 4 + 2) * 68 + r] * rv;
    y[3] += sT[(a * 4 + 3) * 68 + r] * rv;
  }

  // row absmax -> scale
  float m = 0.f;
  #pragma unroll
  for (int u = 0; u < 4; ++u)
    #pragma unroll
    for (int v = 0; v < 4; ++v) m = fmaxf(m, fabsf(y[u][v]));
  #pragma unroll
  for (int off = 32; off > 0; off >>= 1) m = fmaxf(m, __shfl_down(m, off));
  if (lane == 0) sred[w] = m;
  __syncthreads();
  if (tid == 0) {
    const float mm = fmaxf(fmaxf(sred[0], sred[1]), fmaxf(sred[2], sred[3]));
    const float s = fmaxf(mm / QMAX, 1e-8f);
    dscale[row] = s;
    sred[4] = s;
  }
  __syncthreads();
  const float s = sred[4];

  signed char* drow = dst + row * (size_t)HID;
  #pragma unroll
  for (int u = 0; u < 4; ++u) {
    c4 o;
    #pragma unroll
    for (int v = 0; v < 4; ++v) {
      float q = y[u][v] / s;
      q = fminf(fmaxf(q, -QMAX), QMAX);
      q = rintf(q);                 // round-half-even, matches jnp.round
      o[v] = (char)(int)q;
    }
    *(c4*)&drow[(a * 4 + u) * 64 + b * 4] = o;
  }
}

// ---------- 112x128 kron transform + 8-bit fake quant (per row) ----------
__global__ __launch_bounds__(512) void trans112_kernel(
    const float* __restrict__ src, const float* __restrict__ Lm,  // [112][112]
    const float* __restrict__ Rm,                                  // [128][128]
    const float* __restrict__ dia,                                 // [14336]
    signed char* __restrict__ dst, float* __restrict__ dscale, int divide)
{
  __shared__ float sH[112 * 132];  // padded stride 132
  __shared__ float sT[112 * 132];
  __shared__ float sC[16 * 132];   // L/R row-chunk staging
  __shared__ float sred[16];

  const int tid = threadIdx.x;
  const int w = tid >> 6, lane = tid & 63;
  const size_t row = blockIdx.x;
  const float* srow = src + row * (size_t)INTER;

  for (int i = tid * 4; i < INTER; i += 2048) {
    f4 v = *(const f4*)&srow[i];
    f4 d = *(const f4*)&dia[i];
    v = divide ? (v / d) : (v * d);
    const int l = i >> 7, r = i & 127;
    *(f4*)&sH[l * 132 + r] = v;
  }
  __syncthreads();

  const int a = tid >> 5;  // 0..15 -> i block of 7
  const int b = tid & 31;  // 0..31 -> 4-wide col block
  f4 acc[7];
  #pragma unroll
  for (int u = 0; u < 7; ++u) acc[u] = 0.f;

  // phase 1: T1[i][r] = sum_l L[l][i] * H[l][r]
  for (int l0 = 0; l0 < 112; l0 += 16) {
    __syncthreads();
    for (int i = tid; i < 16 * 112; i += 512)
      sC[(i / 112) * 132 + (i % 112)] = Lm[(l0 + i / 112) * 112 + (i % 112)];
    __syncthreads();
    #pragma unroll
    for (int lc = 0; lc < 16; ++lc) {
      const f4 hv = *(const f4*)&sH[(l0 + lc) * 132 + b * 4];
      #pragma unroll
      for (int u = 0; u < 7; ++u)
        acc[u] += sC[lc * 132 + a * 7 + u] * hv;
    }
  }
  #pragma unroll
  for (int u = 0; u < 7; ++u)
    *(f4*)&sT[(a * 7 + u) * 132 + b * 4] = acc[u];

  // phase 2: Y[i][j] = sum_r T1[i][r] * R[r][j]
  f4 y[7];
  #pragma unroll
  for (int u = 0; u < 7; ++u) y[u] = 0.f;
  for (int r0 = 0; r0 < 128; r0 += 16) {
    __syncthreads();  // also publishes sT on first pass, protects sC reuse
    for (int i = tid; i < 16 * 128; i += 512)
      sC[(i >> 7) * 132 + (i & 127)] = Rm[(r0 + (i >> 7)) * 128 + (i & 127)];
    __syncthreads();
    #pragma unroll
    for (int rc = 0; rc < 16; ++rc) {
      const f4 rv = *(const f4*)&sC[rc * 132 + b * 4];
      #pragma unroll
      for (int u = 0; u < 7; ++u)
        y[u] += sT[(a * 7 + u) * 132 + r0 + rc] * rv;
    }
  }

  float m = 0.f;
  #pragma unroll
  for (int u = 0; u < 7; ++u)
    #pragma unroll
    for (int v = 0; v < 4; ++v) m = fmaxf(m, fabsf(y[u][v]));
  #pragma unroll
  for (int off = 32; off > 0; off >>= 1) m = fmaxf(m, __shfl_down(m, off));
  if (lane == 0) sred[w] = m;
  __syncthreads();
  if (tid == 0) {
    float mm = sred[0];
    #pragma unroll
    for (int i = 1; i < 8; ++i) mm = fmaxf(mm, sred[i]);
    const float s = fmaxf(mm / QMAX, 1e-8f);
    dscale[row] = s;
    sred[8] = s;
  }
  __syncthreads();
  const float s = sred[8];

  signed char* drow = dst + row * (size_t)INTER;
  #pragma unroll
  for (int u = 0; u < 7; ++u) {
    c4 o;
    #pragma unroll
    for (int v = 0; v < 4; ++v) {
      float q = y[u][v] / s;
      q = fminf(fmaxf(q, -QMAX), QMAX);
      q = rintf(q);
      o[v] = (char)(int)q;
    }
    *(c4*)&drow[(a * 7 + u) * 128 + b * 4] = o;
  }
}

// ---------- fused up+gate GEMM (int8 MFMA, i32 exact accum) + SwiGLU ----------
// C-tile: 128 rows (tokens) x 64 cols (o) of BOTH matrices; wave = 64x32 of both.
// LDS slot-XOR swizzle (T2, rule #21 both-sides): LDS[row][slot] holds global
// [row][slot ^ (row&7)] (16-B slots). Staging pre-swizzles the GLOBAL source col
// (LDS dest stays linear for global_load_lds); fragment reads apply the same XOR.
// Breaks the 16-way conflict of 128-B-stride rows (37% of cycles, R8 PMC).
__global__ __launch_bounds__(256) void gemm_upgate_kernel(
    const signed char* __restrict__ xq, const signed char* __restrict__ wu,
    const signed char* __restrict__ wg, const float* __restrict__ sx,
    const float* __restrict__ swu, const float* __restrict__ swg,
    float* __restrict__ h)
{
  __shared__ __attribute__((aligned(16))) signed char As[128 * 128];  // 16 KB
  __shared__ __attribute__((aligned(16))) signed char Bu[64 * 128];   // 8 KB
  __shared__ __attribute__((aligned(16))) signed char Bg[64 * 128];   // 8 KB

  const int tid = threadIdx.x;
  const int w = tid >> 6, lane = tid & 63;
  const int quad = lane >> 4, l16 = lane & 15;
  const int wm = w & 1, wn = w >> 1;
  const int n0 = blockIdx.x * 64;
  const int m0 = blockIdx.y * 128;
  const int srow = lane >> 3;                        // row within 8-row staging chunk
  const int scolb = ((lane & 7) * 16) ^ (srow << 4); // pre-swizzled source byte col
  const int sw = (l16 & 7) << 4;                     // read-side XOR (row&7)<<4

  const i32x4 z4 = {0, 0, 0, 0};
  i32x4 accu[4][2], accg[4][2];
  #pragma unroll
  for (int mi = 0; mi < 4; ++mi)
    #pragma unroll
    for (int ni = 0; ni < 2; ++ni) { accu[mi][ni] = z4; accg[mi][ni] = z4; }

  for (int k0 = 0; k0 < HID; k0 += 128) {
    __syncthreads();
    #pragma unroll
    for (int i = 0; i < 4; ++i) {  // A: 16 chunks of 1 KB (128 rows x 128 B)
      const int c = i * 4 + w;
      const int r = c * 8 + srow;
      async_ld16((char*)As + c * 1024,
                 (const char*)xq + (size_t)(m0 + r) * HID + k0 + scolb);
    }
    #pragma unroll
    for (int i = 0; i < 2; ++i) {  // Bu/Bg: 8 chunks each (64 rows x 128 B)
      const int c = i * 4 + w;
      const int r = c * 8 + srow;
      async_ld16((char*)Bu + c * 1024,
                 (const char*)wu + (size_t)(n0 + r) * HID + k0 + scolb);
      async_ld16((char*)Bg + c * 1024,
                 (const char*)wg + (size_t)(n0 + r) * HID + k0 + scolb);
    }
    __syncthreads();  // drains vmcnt -> staged data visible

    #pragma unroll
    for (int kk = 0; kk < 128; kk += 64) {
      const int kb = (kk + quad * 16) ^ sw;  // swizzled byte-in-row
      i32x4 af[4], buf_[2], bgf[2];
      #pragma unroll
      for (int mi = 0; mi < 4; ++mi)
        af[mi] = *(const i32x4*)&As[(wm * 64 + mi * 16 + l16) * 128 + kb];
      #pragma unroll
      for (int ni = 0; ni < 2; ++ni) {
        buf_[ni] = *(const i32x4*)&Bu[(wn * 32 + ni * 16 + l16) * 128 + kb];
        bgf[ni] = *(const i32x4*)&Bg[(wn * 32 + ni * 16 + l16) * 128 + kb];
      }
      #pragma unroll
      for (int mi = 0; mi < 4; ++mi)
        #pragma unroll
        for (int ni = 0; ni < 2; ++ni) {
          accu[mi][ni] = __builtin_amdgcn_mfma_i32_16x16x64_i8(af[mi], buf_[ni], accu[mi][ni], 0, 0, 0);
          accg[mi][ni] = __builtin_amdgcn_mfma_i32_16x16x64_i8(af[mi], bgf[ni], accg[mi][ni], 0, 0, 0);
        }
    }
  }

  // epilogue: dequant scales + SwiGLU, store h fp32
  #pragma unroll
  for (int mi = 0; mi < 4; ++mi) {
    const int tb = m0 + wm * 64 + mi * 16 + quad * 4;
    float sxv[4];
    #pragma unroll
    for (int r = 0; r < 4; ++r) sxv[r] = sx[tb + r];
    #pragma unroll
    for (int ni = 0; ni < 2; ++ni) {
      const int o = n0 + wn * 32 + ni * 16 + l16;
      const float su = swu[o], sg = swg[o];
      #pragma unroll
      for (int r = 0; r < 4; ++r) {
        const float uv = (float)accu[mi][ni][r] * sxv[r] * su;
        const float gv = (float)accg[mi][ni][r] * sxv[r] * sg;
        const float hv = gv / (1.f + __expf(-gv)) * uv;  // silu(g)*u
        h[(size_t)(tb + r) * INTER + o] = hv;
      }
    }
  }
}

// ---------- down GEMM (int8 MFMA), 128x128 tile, same slot-XOR swizzle ----------
__global__ __launch_bounds__(256) void gemm_down_kernel(
    const signed char* __restrict__ hq, const signed char* __restrict__ wd,
    const float* __restrict__ sh, const float* __restrict__ swd,
    float* __restrict__ out)
{
  __shared__ __attribute__((aligned(16))) signed char As[128 * 128];  // 16 KB
  __shared__ __attribute__((aligned(16))) signed char Bs[128 * 128];  // 16 KB

  const int tid = threadIdx.x;
  const int w = tid >> 6, lane = tid & 63;
  const int quad = lane >> 4, l16 = lane & 15;
  const int wm = w & 1, wn = w >> 1;
  const int n0 = blockIdx.x * 128;
  const int m0 = blockIdx.y * 128;
  const int srow = lane >> 3;
  const int scolb = ((lane & 7) * 16) ^ (srow << 4);
  const int sw = (l16 & 7) << 4;

  const i32x4 z4 = {0, 0, 0, 0};
  i32x4 acc[4][4];
  #pragma unroll
  for (int mi = 0; mi < 4; ++mi)
    #pragma unroll
    for (int ni = 0; ni < 4; ++ni) acc[mi][ni] = z4;

  for (int k0 = 0; k0 < INTER; k0 += 128) {
    __syncthreads();
    #pragma unroll
    for (int i = 0; i < 4; ++i) {
      const int c = i * 4 + w;
      const int r = c * 8 + srow;
      async_ld16((char*)As + c * 1024,
                 (const char*)hq + (size_t)(m0 + r) * INTER + k0 + scolb);
      async_ld16((char*)Bs + c * 1024,
                 (const char*)wd + (size_t)(n0 + r) * INTER + k0 + scolb);
    }
    __syncthreads();

    #pragma unroll
    for (int kk = 0; kk < 128; kk += 64) {
      const int kb = (kk + quad * 16) ^ sw;
      i32x4 af[4], bf_[4];
      #pragma unroll
      for (int mi = 0; mi < 4; ++mi)
        af[mi] = *(const i32x4*)&As[(wm * 64 + mi * 16 + l16) * 128 + kb];
      #pragma unroll
      for (int ni = 0; ni < 4; ++ni)
        bf_[ni] = *(const i32x4*)&Bs[(wn * 64 + ni * 16 + l16) * 128 + kb];
      #pragma unroll
      for (int mi = 0; mi < 4; ++mi)
        #pragma unroll
        for (int ni = 0; ni < 4; ++ni)
          acc[mi][ni] = __builtin_amdgcn_mfma_i32_16x16x64_i8(af[mi], bf_[ni], acc[mi][ni], 0, 0, 0);
    }
  }

  #pragma unroll
  for (int mi = 0; mi < 4; ++mi) {
    const int tb = m0 + wm * 64 + mi * 16 + quad * 4;
    float shv[4];
    #pragma unroll
    for (int r = 0; r < 4; ++r) shv[r] = sh[tb + r];
    #pragma unroll
    for (int ni = 0; ni < 4; ++ni) {
      const int o = n0 + wn * 64 + ni * 16 + l16;
      const float sw2 = swd[o];
      #pragma unroll
      for (int r = 0; r < 4; ++r)
        out[(size_t)(tb + r) * HID + o] = (float)acc[mi][ni][r] * shv[r] * sw2;
    }
  }
}

// ---------- launch ----------
extern "C" void kernel_launch(void* const* d_in, const int* in_sizes, int n_in,
                              void* d_out, int out_size, void* d_ws, size_t ws_size,
                              hipStream_t stream) {
  const float* x      = (const float*)d_in[0];
  const float* w_up   = (const float*)d_in[1];
  const float* w_gate = (const float*)d_in[2];
  const float* w_down = (const float*)d_in[3];
  const float* ugL    = (const float*)d_in[4];
  const float* ugR    = (const float*)d_in[5];
  const float* ugd    = (const float*)d_in[6];
  const float* dnL    = (const float*)d_in[7];
  const float* dnR    = (const float*)d_in[8];
  const float* dnd    = (const float*)d_in[9];

  char* ws = (char*)d_ws;
  size_t off = 0;
  auto alloc = [&](size_t bytes) {
    char* p = ws + off;
    off = (off + bytes + 255) & ~(size_t)255;
    return p;
  };
  signed char* wqu = (signed char*)alloc((size_t)INTER * HID);        // 58.7 MB
  signed char* wqg = (signed char*)alloc((size_t)INTER * HID);        // 58.7 MB
  signed char* wqd = (signed char*)alloc((size_t)HID * INTER);        // 58.7 MB
  signed char* xq  = (signed char*)alloc((size_t)4096 * HID);         // 16.8 MB
  signed char* hq  = (signed char*)alloc((size_t)4096 * INTER);       // 58.7 MB
  float* hbuf = (float*)alloc((size_t)4096 * INTER * 4);              // 235 MB
  float* sxs  = (float*)alloc((size_t)4096 * 4);
  float* swu  = (float*)alloc((size_t)INTER * 4);
  float* swg  = (float*)alloc((size_t)INTER * 4);
  float* swd  = (float*)alloc((size_t)HID * 4);
  float* shs  = (float*)alloc((size_t)4096 * 4);

  // weight prep (orthogonal L,R: inv == transpose, so weight transform == L^T (W/d) R)
  hipLaunchKernelGGL(trans64_kernel, dim3(INTER), dim3(256), 0, stream,
                     w_up, ugL, ugR, ugd, wqu, swu, 1);
  hipLaunchKernelGGL(trans64_kernel, dim3(INTER), dim3(256), 0, stream,
                     w_gate, ugL, ugR, ugd, wqg, swg, 1);
  hipLaunchKernelGGL(trans112_kernel, dim3(HID), dim3(512), 0, stream,
                     w_down, dnL, dnR, dnd, wqd, swd, 1);
  // activation transform + quant
  hipLaunchKernelGGL(trans64_kernel, dim3(4096), dim3(256), 0, stream,
                     x, ugL, ugR, ugd, xq, sxs, 0);
  // fused up/gate GEMM + SwiGLU
  hipLaunchKernelGGL(gemm_upgate_kernel, dim3(INTER / 64, 4096 / 128), dim3(256), 0, stream,
                     xq, wqu, wqg, sxs, swu, swg, hbuf);
  // h transform + quant
  hipLaunchKernelGGL(trans112_kernel, dim3(4096), dim3(512), 0, stream,
                     hbuf, dnL, dnR, dnd, hq, shs, 0);
  // down GEMM -> out
  hipLaunchKernelGGL(gemm_down_kernel, dim3(HID / 128, 4096 / 128), dim3(256), 0, stream,
                     hq, wqd, shs, swd, (float*)d_out);
}